// Round 8
// baseline (156.062 us; speedup 1.0000x reference)
//
#include <hip/hip_runtime.h>

// Additive attention, factored:
//   scores[b,q,k] = sum_h w_h * tanh(qp+kp) ;  tanh(x) = 1 - 2/(1+e^{2x})
//   e^{2(qp+kp)} = Eq*Ek  (Eq=e^{2qp}, Ek=e^{2kp} precomputed)
// With a = sum_h w_h/(1+Eq*Ek): score = const - 2a  ->  min-form softmax:
// p = exp2((min_a - a)*2*log2e). Inner loop = fma+rcp+fma per (q,k,h).
//
// K0: repack W -> W4T[g][h] float4 (g = d/4).
// K1: proj+exp (round-7: swizzled W LDS, 4-way max conflicts).
// K2: fused scores + masked softmax + P@V per (b, 4q).
//     *** b is the SLOWEST block index: consecutive blocks round-robin
//     across XCDs, so b-fastest pinned each batch to one XCD (round-7 bug:
//     23% occupancy). b-slowest spreads every batch over all XCDs. ***
//     Thread = 4 k (float4 ek) x 4 q: 192 VALU cyc per 16 B load.

#define Bb 8
#define Qn 256
#define Kk 1024
#define Dd 256
#define Hh 128
#define DVv 128

__device__ __forceinline__ float fexp2(float x) { return __builtin_amdgcn_exp2f(x); }
__device__ __forceinline__ float frcp(float x)  { return __builtin_amdgcn_rcpf(x); }

// ---------------------------------------------------------------------------
// K0: W [H][D] -> W4T [D/4][H] float4. 64 blocks x 256 threads.
// ---------------------------------------------------------------------------
__global__ __launch_bounds__(256)
void repack_w(const float* __restrict__ Wq, const float* __restrict__ Wk,
              float4* __restrict__ Wq4T, float4* __restrict__ Wk4T)
{
    const int blk = blockIdx.x;
    const float* src = (blk < 32) ? Wq : Wk;
    float4*      dst = (blk < 32) ? Wq4T : Wk4T;
    const int idx = (blk & 31) * 256 + threadIdx.x;   // 8192 float4 per matrix
    const int g = idx >> 7;
    const int h = idx & 127;
    dst[idx] = *(const float4*)(src + (size_t)h * Dd + g * 4);
}

// ---------------------------------------------------------------------------
// K1: EqT[b][h][r] = exp2(2*log2e * X[r]·W[h]).
// 320 blocks x 256 threads. Block = 32 rows x 128 h; thread = 4 rows x 4 h.
// W LDS layout swizzled: slot(h) = (h&3)*32 + (h>>2) -> 4-way max conflicts.
// ---------------------------------------------------------------------------
__global__ __launch_bounds__(256, 2)
void proj_exp_kernel(const float* __restrict__ queries,
                     const float* __restrict__ keys,
                     const float4* __restrict__ Wq4T,
                     const float4* __restrict__ Wk4T,
                     float* __restrict__ EqT,
                     float* __restrict__ EkT)
{
    __shared__ float  Xs[32 * 256];      // 32 KB  [row][d]
    __shared__ float4 Ws4[16 * 128];     // 32 KB  [g-in-chunk][swizzled h]

    const int blk = blockIdx.x;          // 0..63 queries, 64..319 keys
    const float* X; const float4* W4; float* outT; int RB; int i0;
    if (blk < 64) { X = queries; W4 = Wq4T; outT = EqT; RB = Qn; i0 = blk * 32; }
    else          { X = keys;    W4 = Wk4T; outT = EkT; RB = Kk; i0 = (blk - 64) * 32; }

    const int tid = threadIdx.x;
    const int hq  = tid & 31;            // h-quad: h = 4*hq + j
    const int rg  = tid >> 5;            // row-group: r0 = 4*rg
    const int h0  = hq * 4;

    // stage full X tile: 32 rows x 256 d = 2048 float4, 8 per thread
#pragma unroll
    for (int s = 0; s < 8; ++s) {
        const int idx = tid + 256 * s;
        const int row = idx >> 6, c4 = (idx & 63) * 4;
        *(float4*)(Xs + row * 256 + c4) =
            *(const float4*)(X + (size_t)(i0 + row) * Dd + c4);
    }

    float acc[4][4];                     // [row][h]
#pragma unroll
    for (int i = 0; i < 4; ++i)
#pragma unroll
        for (int j = 0; j < 4; ++j) acc[i][j] = 0.f;

    for (int c = 0; c < 4; ++c) {        // 4 chunks of 64 d (16 g)
        const int g0 = c * 16;
        __syncthreads();                 // protects Xs (1st iter) / Ws4 reuse
#pragma unroll
        for (int s = 0; s < 8; ++s) {    // stage W chunk, slot-contiguous writes
            const int idx  = tid + 256 * s;
            const int g    = idx >> 7;
            const int slot = idx & 127;                       // j*32 + hq
            const int h    = ((slot & 31) << 2) | (slot >> 5);// inverse swizzle
            Ws4[idx] = W4[(size_t)(g0 + g) * Hh + h];
        }
        __syncthreads();

#pragma unroll 4
        for (int g = 0; g < 16; ++g) {
            float4 x[4], w[4];
#pragma unroll
            for (int i = 0; i < 4; ++i)  // 2 addrs per wave -> broadcast
                x[i] = *(const float4*)(Xs + (rg * 4 + i) * 256 + (g0 + g) * 4);
#pragma unroll
            for (int j = 0; j < 4; ++j)  // swizzled: 4B lane stride, 4-way
                w[j] = Ws4[g * 128 + j * 32 + hq];
#pragma unroll
            for (int i = 0; i < 4; ++i)
#pragma unroll
                for (int j = 0; j < 4; ++j) {
                    acc[i][j] = fmaf(x[i].x, w[j].x, acc[i][j]);
                    acc[i][j] = fmaf(x[i].y, w[j].y, acc[i][j]);
                    acc[i][j] = fmaf(x[i].z, w[j].z, acc[i][j]);
                    acc[i][j] = fmaf(x[i].w, w[j].w, acc[i][j]);
                }
        }
    }

    const int b    = i0 / RB;            // 32 | RB, never straddles b
    const int rloc = (i0 % RB) + rg * 4;
#pragma unroll
    for (int j = 0; j < 4; ++j) {
        float4 o;
        o.x = fexp2(acc[0][j] * 2.885390082f);   // e^{2x} = 2^{2x*log2e}
        o.y = fexp2(acc[1][j] * 2.885390082f);
        o.z = fexp2(acc[2][j] * 2.885390082f);
        o.w = fexp2(acc[3][j] * 2.885390082f);
        *(float4*)(outT + (size_t)b * Hh * RB + (size_t)(h0 + j) * RB + rloc) = o;
    }
}

// ---------------------------------------------------------------------------
// K2: fused scores + masked softmax + P@V.
// 512 blocks x 256 threads; blk = b*64 + qg  (b SLOWEST -> XCD-uniform).
// Block = (b, q0..q0+3). Phase 1: thread = 4 k x 4 q, one float4 ek load
// per h feeding 192 VALU cycles. Phase 2: 4 waves own 4 q. Phase 3: 4-q PV.
// ---------------------------------------------------------------------------
#define QSTEP(ACC, EQS, W, EK)                                \
    ACC.x = fmaf(W, frcp(fmaf(EQS, EK.x, 1.0f)), ACC.x);      \
    ACC.y = fmaf(W, frcp(fmaf(EQS, EK.y, 1.0f)), ACC.y);      \
    ACC.z = fmaf(W, frcp(fmaf(EQS, EK.z, 1.0f)), ACC.z);      \
    ACC.w = fmaf(W, frcp(fmaf(EQS, EK.w, 1.0f)), ACC.w);

__global__ __launch_bounds__(256, 2)
void attn_kernel(const float* __restrict__ EqT,
                 const float* __restrict__ EkT,
                 const float* __restrict__ wv,
                 const float* __restrict__ values,
                 const int* __restrict__ valid_lens,
                 float* __restrict__ out)
{
    __shared__ float4 eqpk[Hh];          // 2 KB: Eq for the 4 q, per h
    __shared__ float  wvs[Hh];           // 0.5 KB
    __shared__ float  s_a[4][Kk];        // 16 KB: a-scores then weights
    __shared__ float4 s_part[3][4][32];  // 6 KB: PV partials
    __shared__ float  s_inv[4];

    const int blk  = blockIdx.x;
    const int b    = blk >> 6;           // SLOWEST -> uniform over XCDs
    const int q0   = (blk & 63) << 2;
    const int tid  = threadIdx.x;
    const int lane = tid & 63;
    const int wave = __builtin_amdgcn_readfirstlane(tid >> 6);
    const int len  = valid_lens[b];

    // ---- stage per-h constants (one-time)
    if (tid < Hh) {
        eqpk[tid] = *(const float4*)(EqT + (size_t)b * Hh * Qn + (size_t)tid * Qn + q0);
        wvs[tid]  = wv[tid];
    }
    __syncthreads();

    // ---- phase 1: a[q][k] = sum_h wv[h]/(1+Eq*Ek); thread = 4 k x 4 q
    const int k4 = tid * 4;
    if (k4 < len) {
        const float4* ekp4 = (const float4*)(EkT + (size_t)b * Hh * Kk + k4);
        float4 a0 = {0.f,0.f,0.f,0.f}, a1 = {0.f,0.f,0.f,0.f};
        float4 a2 = {0.f,0.f,0.f,0.f}, a3 = {0.f,0.f,0.f,0.f};
#pragma unroll 2
        for (int h = 0; h < Hh; h += 2) {
            const float4 ekA = ekp4[(size_t)(h + 0) * 256];   // Kk/4 stride
            const float4 ekB = ekp4[(size_t)(h + 1) * 256];
            const float4 eA  = eqpk[h + 0];
            const float4 eB  = eqpk[h + 1];
            const float  wA  = wvs[h + 0];
            const float  wB  = wvs[h + 1];
            QSTEP(a0, eA.x, wA, ekA)
            QSTEP(a1, eA.y, wA, ekA)
            QSTEP(a2, eA.z, wA, ekA)
            QSTEP(a3, eA.w, wA, ekA)
            QSTEP(a0, eB.x, wB, ekB)
            QSTEP(a1, eB.y, wB, ekB)
            QSTEP(a2, eB.z, wB, ekB)
            QSTEP(a3, eB.w, wB, ekB)
        }
        *(float4*)(&s_a[0][k4]) = a0;
        *(float4*)(&s_a[1][k4]) = a1;
        *(float4*)(&s_a[2][k4]) = a2;
        *(float4*)(&s_a[3][k4]) = a3;
    }
    __syncthreads();

    // ---- phase 2: min-form softmax; wave w owns q = w
    {
        const int q = wave;
        float mn = 3.0e38f;
        for (int i = lane; i < len; i += 64) mn = fminf(mn, s_a[q][i]);
#pragma unroll
        for (int off = 32; off > 0; off >>= 1) mn = fminf(mn, __shfl_xor(mn, off));
        float sum = 0.f;
        for (int i = lane; i < len; i += 64) {
            const float p = fexp2((mn - s_a[q][i]) * 2.885390082f);
            s_a[q][i] = p;
            sum += p;
        }
#pragma unroll
        for (int off = 32; off > 0; off >>= 1) sum += __shfl_xor(sum, off);
        if (lane == 0) s_inv[q] = frcp(sum);
    }
    __syncthreads();

    // ---- phase 3: P@V. 8 k-slices x (32 lanes x float4 = 128 v)
    {
        const int slice = tid >> 5;
        const int l32   = tid & 31;
        const int v4    = l32 << 2;
        const float* vp = values + (size_t)b * Kk * DVv + v4;
        float4 a0 = {0.f,0.f,0.f,0.f}, a1 = {0.f,0.f,0.f,0.f};
        float4 a2 = {0.f,0.f,0.f,0.f}, a3 = {0.f,0.f,0.f,0.f};
        for (int k = slice; k < len; k += 8) {
            const float4 val = *(const float4*)(vp + (size_t)k * DVv);
            const float w0 = s_a[0][k];  // same k per 32-lane slice -> broadcast
            const float w1 = s_a[1][k];
            const float w2 = s_a[2][k];
            const float w3 = s_a[3][k];
            a0.x = fmaf(w0, val.x, a0.x); a0.y = fmaf(w0, val.y, a0.y);
            a0.z = fmaf(w0, val.z, a0.z); a0.w = fmaf(w0, val.w, a0.w);
            a1.x = fmaf(w1, val.x, a1.x); a1.y = fmaf(w1, val.y, a1.y);
            a1.z = fmaf(w1, val.z, a1.z); a1.w = fmaf(w1, val.w, a1.w);
            a2.x = fmaf(w2, val.x, a2.x); a2.y = fmaf(w2, val.y, a2.y);
            a2.z = fmaf(w2, val.z, a2.z); a2.w = fmaf(w2, val.w, a2.w);
            a3.x = fmaf(w3, val.x, a3.x); a3.y = fmaf(w3, val.y, a3.y);
            a3.z = fmaf(w3, val.z, a3.z); a3.w = fmaf(w3, val.w, a3.w);
        }
#pragma unroll
        for (int off = 32; off < 64; off <<= 1) { /* fold slice pairs in wave */ }
        a0.x += __shfl_xor(a0.x, 32); a0.y += __shfl_xor(a0.y, 32);
        a0.z += __shfl_xor(a0.z, 32); a0.w += __shfl_xor(a0.w, 32);
        a1.x += __shfl_xor(a1.x, 32); a1.y += __shfl_xor(a1.y, 32);
        a1.z += __shfl_xor(a1.z, 32); a1.w += __shfl_xor(a1.w, 32);
        a2.x += __shfl_xor(a2.x, 32); a2.y += __shfl_xor(a2.y, 32);
        a2.z += __shfl_xor(a2.z, 32); a2.w += __shfl_xor(a2.w, 32);
        a3.x += __shfl_xor(a3.x, 32); a3.y += __shfl_xor(a3.y, 32);
        a3.z += __shfl_xor(a3.z, 32); a3.w += __shfl_xor(a3.w, 32);
        if (wave > 0 && lane < 32) {
            s_part[wave - 1][0][l32] = a0;
            s_part[wave - 1][1][l32] = a1;
            s_part[wave - 1][2][l32] = a2;
            s_part[wave - 1][3][l32] = a3;
        }
        __syncthreads();
        if (wave == 0 && lane < 32) {
            float4 r[4] = {a0, a1, a2, a3};
#pragma unroll
            for (int q = 0; q < 4; ++q) {
#pragma unroll
                for (int w = 0; w < 3; ++w) {
                    const float4 p = s_part[w][q][l32];
                    r[q].x += p.x; r[q].y += p.y; r[q].z += p.z; r[q].w += p.w;
                }
                const float inv = s_inv[q];
                *(float4*)(out + (size_t)(b * Qn + q0 + q) * DVv + v4) =
                    make_float4(r[q].x * inv, r[q].y * inv, r[q].z * inv, r[q].w * inv);
            }
        }
    }
}

extern "C" void kernel_launch(void* const* d_in, const int* in_sizes, int n_in,
                              void* d_out, int out_size, void* d_ws, size_t ws_size,
                              hipStream_t stream) {
    (void)in_sizes; (void)n_in; (void)out_size; (void)ws_size;
    const float* queries    = (const float*)d_in[0];
    const float* keys       = (const float*)d_in[1];
    const float* values     = (const float*)d_in[2];
    const int*   valid_lens = (const int*)  d_in[3];
    const float* Wq         = (const float*)d_in[4];
    const float* Wk         = (const float*)d_in[5];
    const float* wvv        = (const float*)d_in[6];
    float* out = (float*)d_out;

    float* Wq4T = (float*)d_ws;                                  // 256*128 floats
    float* Wk4T = Wq4T + (size_t)Dd * Hh;
    float* EqT  = Wk4T + (size_t)Dd * Hh;                        // 8*128*256
    float* EkT  = EqT + (size_t)Bb * Hh * Qn;                    // 8*128*1024

    repack_w       <<< 64, 256, 0, stream>>>(Wq, Wk, (float4*)Wq4T, (float4*)Wk4T);
    proj_exp_kernel<<<320, 256, 0, stream>>>(queries, keys, (const float4*)Wq4T,
                                             (const float4*)Wk4T, EqT, EkT);
    attn_kernel    <<<512, 256, 0, stream>>>(EqT, EkT, wvv, values, valid_lens, out);
}